// Round 1
// baseline (80.285 us; speedup 1.0000x reference)
//
#include <hip/hip_runtime.h>

#define K 16           // num_states
#define CH 32          // scan chunk size
#define MAXN 512       // max sentence length supported (n/CH <= 16 chunks)

// Stage 1: compute stacked[n][16] where stacked[i] = sum_{j=0}^{n-1-i} T^j v.
// Single block, 256 threads.
__global__ __launch_bounds__(256) void pe_stage1(
    const float* __restrict__ pos_initial,
    const float* __restrict__ pos_transition,
    float* __restrict__ stacked, int n)
{
    __shared__ float sT[K][K];            // T
    __shared__ float sA[K][K];            // squaring ping
    __shared__ float sB[K][K];            // squaring pong
    __shared__ float sP[CH][K];           // p_b = sum_{j<=b} T^j v, b=0..31
    __shared__ float sMp[MAXN/CH][K][K];  // M^a, M = T^32
    __shared__ float sG[MAXN/CH][K];      // g_a = M^a p31
    __shared__ float sU[MAXN/CH][K];      // u_a = sum_{a'<a} g_{a'}
    __shared__ float sV[K];

    const int tid = threadIdx.x;
    const int r8 = tid >> 4, c8 = tid & 15;   // (row, col) for 256-thread matrix ops

    // Phase 0: load T, v
    if (tid < K * K) sT[r8][c8] = pos_transition[tid];
    if (tid < K)     sV[tid] = pos_initial[tid];
    __syncthreads();

    // Phase 1: wave 0 runs the 32-step matvec chain; all 64 lanes replicate
    // rows mod 16 so __shfl(s, c) (c<16) is valid for every lane.
    if (tid < 64) {
        const int r = tid & 15;
        float trow[K];
        #pragma unroll
        for (int c = 0; c < K; ++c) trow[c] = sT[r][c];
        float s = sV[r];      // c_0 = v
        float p = s;          // p_0
        if (tid < K) sP[0][r] = p;
        for (int j = 1; j < CH; ++j) {
            float sn = 0.f;
            #pragma unroll
            for (int c = 0; c < K; ++c) sn += trow[c] * __shfl(s, c);
            s = sn;           // c_j = T c_{j-1}
            p += s;
            if (tid < K) sP[j][r] = p;
        }
    }
    __syncthreads();

    // Phase 2: M = T^32 via 5 squarings (each: 256 threads, one element each).
    {
        float acc;
        // T^2 : sT -> sA
        acc = 0.f;
        #pragma unroll
        for (int k2 = 0; k2 < K; ++k2) acc += sT[r8][k2] * sT[k2][c8];
        sA[r8][c8] = acc; __syncthreads();
        // T^4 : sA -> sB
        acc = 0.f;
        #pragma unroll
        for (int k2 = 0; k2 < K; ++k2) acc += sA[r8][k2] * sA[k2][c8];
        sB[r8][c8] = acc; __syncthreads();
        // T^8 : sB -> sA
        acc = 0.f;
        #pragma unroll
        for (int k2 = 0; k2 < K; ++k2) acc += sB[r8][k2] * sB[k2][c8];
        sA[r8][c8] = acc; __syncthreads();
        // T^16 : sA -> sB
        acc = 0.f;
        #pragma unroll
        for (int k2 = 0; k2 < K; ++k2) acc += sA[r8][k2] * sA[k2][c8];
        sB[r8][c8] = acc; __syncthreads();
        // T^32 : sB -> sA   (M lives in sA)
        acc = 0.f;
        #pragma unroll
        for (int k2 = 0; k2 < K; ++k2) acc += sB[r8][k2] * sB[k2][c8];
        sA[r8][c8] = acc; __syncthreads();
    }

    // Phase 3: scan M^a (a = 0..NA-1), then g_a = M^a p31, u_a = prefix(g).
    const int NA = ((n - 1) >> 5) + 1;   // #chunks (<= 16)
    sMp[0][r8][c8] = (r8 == c8) ? 1.f : 0.f;
    __syncthreads();
    for (int a = 1; a < NA; ++a) {
        float acc = 0.f;
        #pragma unroll
        for (int k2 = 0; k2 < K; ++k2) acc += sMp[a-1][r8][k2] * sA[k2][c8];
        sMp[a][r8][c8] = acc;
        __syncthreads();
    }
    if (tid < NA * K) {
        const int a = r8, r = c8;
        float acc = 0.f;
        #pragma unroll
        for (int c = 0; c < K; ++c) acc += sMp[a][r][c] * sP[CH-1][c];
        sG[a][r] = acc;
    }
    __syncthreads();
    if (tid < NA * K) {
        const int a = r8, r = c8;
        float acc = 0.f;
        for (int a2 = 0; a2 < a; ++a2) acc += sG[a2][r];
        sU[a][r] = acc;
    }
    __syncthreads();

    // Phase 4: stacked[i][r] = u_a[r] + M^a p_b, with m-1 = n-1-i = 32a + b.
    for (int idx = tid; idx < n * K; idx += 256) {
        const int i = idx >> 4, r = idx & 15;
        const int m1 = n - 1 - i;
        const int a  = m1 >> 5, bb = m1 & (CH - 1);
        float acc = sU[a][r];
        #pragma unroll
        for (int c = 0; c < K; ++c) acc += sMp[a][r][c] * sP[bb][c];
        stacked[idx] = acc;
    }
}

// Stage 2: pe[i][e] = dot(stacked[i], W[e]) + b[e].  One block per row i.
__global__ __launch_bounds__(256) void pe_stage2(
    const float* __restrict__ stacked,
    const float* __restrict__ W,
    const float* __restrict__ bias,
    float* __restrict__ out, int E)
{
    __shared__ float srow[K];
    const int i = blockIdx.x;
    const int tid = threadIdx.x;
    if (tid < K) srow[tid] = stacked[i * K + tid];
    __syncthreads();
    for (int e = tid; e < E; e += 256) {
        const float4* w4 = reinterpret_cast<const float4*>(W + e * K);
        float4 w0 = w4[0], w1 = w4[1], w2 = w4[2], w3 = w4[3];
        float acc = bias[e];
        acc += w0.x * srow[0]  + w0.y * srow[1]  + w0.z * srow[2]  + w0.w * srow[3];
        acc += w1.x * srow[4]  + w1.y * srow[5]  + w1.z * srow[6]  + w1.w * srow[7];
        acc += w2.x * srow[8]  + w2.y * srow[9]  + w2.z * srow[10] + w2.w * srow[11];
        acc += w3.x * srow[12] + w3.y * srow[13] + w3.z * srow[14] + w3.w * srow[15];
        out[i * E + e] = acc;
    }
}

extern "C" void kernel_launch(void* const* d_in, const int* in_sizes, int n_in,
                              void* d_out, int out_size, void* d_ws, size_t ws_size,
                              hipStream_t stream) {
    const float* pos_initial    = (const float*)d_in[0];  // [16,1]
    const float* pos_transition = (const float*)d_in[1];  // [16,16]
    const float* W              = (const float*)d_in[2];  // [512,16]
    const float* bias           = (const float*)d_in[3];  // [512]
    // d_in[4] = sentence_len on device; derive n on host from out_size instead.
    const int E = in_sizes[3];          // embed_dim = 512
    const int n = out_size / E;         // seq_len  = 512

    float* stacked = (float*)d_ws;      // n*16 floats = 32 KB

    pe_stage1<<<1, 256, 0, stream>>>(pos_initial, pos_transition, stacked, n);
    pe_stage2<<<n, 256, 0, stream>>>(stacked, W, bias, (float*)d_out, E);
}

// Round 2
// 70.355 us; speedup vs baseline: 1.1411x; 1.1411x over previous
//
#include <hip/hip_runtime.h>

#define K 16      // num_states
#define KP 17     // padded leading dim (bank-conflict-free column reads)
#define MAXN 512  // max supported sentence length

// Fully fused: each block computes the whole prefix-vector scan redundantly
// (log-depth, in LDS), then writes one output row pe[i] = stacked[i] @ W^T + b,
// where stacked[i] = p_{n-1-i},  p_j = sum_{t=0}^{j} T^t v.
//
// Doubling recurrence:  p_{j+s} = p_{s-1} + T^s p_j   (j = 0..s-1)
// with T^{2s} = (T^s)^2 computed concurrently in the same barrier interval.
__global__ __launch_bounds__(256) void pe_fused(
    const float* __restrict__ pos_initial,     // [16,1]
    const float* __restrict__ pos_transition,  // [16,16]
    const float* __restrict__ W,               // [E,16]
    const float* __restrict__ bias,            // [E]
    float* __restrict__ out, int n, int E)
{
    __shared__ float sPow[2][K][KP];  // T^{2^m} ping-pong, padded
    __shared__ float sP[MAXN][K];     // prefix vectors p_0..p_{n-1}

    const int tid = threadIdx.x;
    const int r8 = tid >> 4, c8 = tid & 15;

    // load T and p_0 = v
    if (tid < K * K) sPow[0][r8][c8] = pos_transition[tid];
    if (tid < K)     sP[0][tid] = pos_initial[tid];
    __syncthreads();

    int cur = 0;
    for (int s = 1; s < n; s <<= 1) {
        const float (*Tm)[KP] = sPow[cur];

        // (a) squaring T^{2s} = (T^s)^2 — 256 threads, one element each.
        //     Column read Tm[k2][c8] is conflict-free thanks to KP=17 pad.
        float sq = 0.f;
        #pragma unroll
        for (int k2 = 0; k2 < K; ++k2) sq += Tm[r8][k2] * Tm[k2][c8];

        // (b) scan step: produce p_s .. p_{min(2s,n)-1}
        const int jmax = (s < n - s) ? s : (n - s);
        for (int e = tid; e < jmax * K; e += 256) {
            const int j = e >> 4, r = e & 15;
            float acc = sP[s - 1][r];
            #pragma unroll
            for (int c = 0; c < K; ++c) acc += Tm[r][c] * sP[j][c];
            sP[j + s][r] = acc;  // writes [s, 2s): disjoint from reads [0, s)
        }

        sPow[cur ^ 1][r8][c8] = sq;  // not read until after the barrier
        cur ^= 1;
        __syncthreads();
    }

    // Epilogue: this block's row i; stacked[i] = p_{n-1-i}
    const int i = blockIdx.x;
    const int m1 = n - 1 - i;
    float srow[K];
    #pragma unroll
    for (int r = 0; r < K; ++r) srow[r] = sP[m1][r];  // broadcast reads

    for (int e = tid; e < E; e += 256) {
        const float4* w4 = reinterpret_cast<const float4*>(W + e * K);
        float4 w0 = w4[0], w1 = w4[1], w2 = w4[2], w3 = w4[3];
        float acc = bias[e];
        acc += w0.x * srow[0]  + w0.y * srow[1]  + w0.z * srow[2]  + w0.w * srow[3];
        acc += w1.x * srow[4]  + w1.y * srow[5]  + w1.z * srow[6]  + w1.w * srow[7];
        acc += w2.x * srow[8]  + w2.y * srow[9]  + w2.z * srow[10] + w2.w * srow[11];
        acc += w3.x * srow[12] + w3.y * srow[13] + w3.z * srow[14] + w3.w * srow[15];
        out[i * E + e] = acc;
    }
}

extern "C" void kernel_launch(void* const* d_in, const int* in_sizes, int n_in,
                              void* d_out, int out_size, void* d_ws, size_t ws_size,
                              hipStream_t stream) {
    const float* pos_initial    = (const float*)d_in[0];  // [16,1]
    const float* pos_transition = (const float*)d_in[1];  // [16,16]
    const float* W              = (const float*)d_in[2];  // [512,16]
    const float* bias           = (const float*)d_in[3];  // [512]
    const int E = in_sizes[3];          // embed_dim = 512
    const int n = out_size / E;         // seq_len  = 512

    pe_fused<<<n, 256, 0, stream>>>(pos_initial, pos_transition, W, bias,
                                    (float*)d_out, n, E);
}

// Round 3
// 68.537 us; speedup vs baseline: 1.1714x; 1.0265x over previous
//
#include <hip/hip_runtime.h>

#define K 16
#define RP 20            // padded row stride in floats: 80 B = 16B-aligned, bank-safe
#define MAXN 512

static __device__ __forceinline__ float dot4(float4 a, float4 b) {
    return a.x * b.x + a.y * b.y + a.z * b.z + a.w * b.w;
}

// Fully fused automaton PE. Each block redundantly runs the log-depth prefix
// scan p_j = sum_{t<=j} T^t v in LDS (vectorized b128), then emits 2 output
// rows: pe[i] = p_{n-1-i} @ W^T + b.
__global__ __launch_bounds__(256) void pe_fused(
    const float* __restrict__ pos_initial,     // [16,1]
    const float* __restrict__ pos_transition,  // [16,16]
    const float* __restrict__ Wm,              // [E,16]
    const float* __restrict__ bias,            // [E]
    float* __restrict__ out, int n, int E, int nb)
{
    __shared__ float sA [2][K][RP];   // T^(2^m) ping-pong
    __shared__ float sAT[2][K][RP];   // its transpose (b128 column reads)
    __shared__ float sP [MAXN][RP];   // prefix vectors

    const int tid = threadIdx.x;
    const int r8 = tid >> 4, c8 = tid & 15;

    {   // load T and T^T ; p_0 = v
        float t = pos_transition[r8 * K + c8];
        sA [0][r8][c8] = t;
        sAT[0][c8][r8] = t;
    }
    if (tid < K) sP[0][tid] = pos_initial[tid];
    __syncthreads();

    int cur = 0;
    for (int s = 1; s < n; s <<= 1) {
        // ---- (a) squaring T^{2s} = (T^s)^2, one element/thread, all-b128 reads
        const bool do_sq = (2 * s) < n;
        float sq = 0.f;
        if (do_sq) {
            const float4* ar = (const float4*)&sA [cur][r8][0];
            const float4* ac = (const float4*)&sAT[cur][c8][0];
            sq = dot4(ar[0], ac[0]) + dot4(ar[1], ac[1])
               + dot4(ar[2], ac[2]) + dot4(ar[3], ac[3]);
        }

        // ---- (b) scan: p_{j+s} = p_{s-1} + T^s p_j, j = 0..jmax-1
        const int jmax = (s < n - s) ? s : (n - s);
        const int w = tid >> 6, lane = tid & 63;
        int rg, j0, jstep; bool part;
        if (jmax <= 16) { rg = lane >> 4; j0 = lane & 15; jstep = 16; part = (w == 0); }
        else            { rg = w;         j0 = lane;      jstep = 64; part = true;    }
        if (part && j0 < jmax) {
            // this thread produces rows 4rg..4rg+3; T^s rows cached in VGPRs
            float4 tm[16];
            #pragma unroll
            for (int rr = 0; rr < 4; ++rr) {
                const float4* arow = (const float4*)&sA[cur][4 * rg + rr][0];
                #pragma unroll
                for (int q = 0; q < 4; ++q) tm[rr * 4 + q] = arow[q];
            }
            const float4 b0 = ((const float4*)&sP[s - 1][0])[rg];
            for (int j = j0; j < jmax; j += jstep) {
                const float4* pj = (const float4*)&sP[j][0];
                const float4 p0 = pj[0], p1 = pj[1], p2 = pj[2], p3 = pj[3];
                float4 o;
                o.x = b0.x + dot4(tm[0], p0) + dot4(tm[1], p1) + dot4(tm[2], p2) + dot4(tm[3], p3);
                o.y = b0.y + dot4(tm[4], p0) + dot4(tm[5], p1) + dot4(tm[6], p2) + dot4(tm[7], p3);
                o.z = b0.z + dot4(tm[8], p0) + dot4(tm[9], p1) + dot4(tm[10], p2) + dot4(tm[11], p3);
                o.w = b0.w + dot4(tm[12], p0) + dot4(tm[13], p1) + dot4(tm[14], p2) + dot4(tm[15], p3);
                ((float4*)&sP[j + s][0])[rg] = o;   // rows [s,2s): disjoint from reads
            }
        }

        if (do_sq) {
            sA [cur ^ 1][r8][c8] = sq;   // buffer not read until after barrier
            sAT[cur ^ 1][c8][r8] = sq;
            cur ^= 1;
        }
        __syncthreads();
    }

    // ---- epilogue: rows i = b and b + nb
    const int b = blockIdx.x;
    #pragma unroll
    for (int rep = 0; rep < 2; ++rep) {
        const int i = b + rep * nb;
        if (i < n) {
            const int m1 = n - 1 - i;
            const float4* pm = (const float4*)&sP[m1][0];
            const float4 p0 = pm[0], p1 = pm[1], p2 = pm[2], p3 = pm[3];
            for (int e = tid; e < E; e += 256) {
                const float4* w4 = (const float4*)(Wm + e * K);
                float acc = bias[e] + dot4(w4[0], p0) + dot4(w4[1], p1)
                          + dot4(w4[2], p2) + dot4(w4[3], p3);
                out[i * E + e] = acc;
            }
        }
    }
}

extern "C" void kernel_launch(void* const* d_in, const int* in_sizes, int n_in,
                              void* d_out, int out_size, void* d_ws, size_t ws_size,
                              hipStream_t stream) {
    const float* pos_initial    = (const float*)d_in[0];  // [16,1]
    const float* pos_transition = (const float*)d_in[1];  // [16,16]
    const float* W              = (const float*)d_in[2];  // [512,16]
    const float* bias           = (const float*)d_in[3];  // [512]
    const int E = in_sizes[3];          // embed_dim = 512
    const int n = out_size / E;         // seq_len  = 512
    const int nb = (n + 1) / 2;         // blocks; 2 rows each -> 1 block/CU

    pe_fused<<<nb, 256, 0, stream>>>(pos_initial, pos_transition, W, bias,
                                     (float*)d_out, n, E, nb);
}